// Round 3
// baseline (416.764 us; speedup 1.0000x reference)
//
#include <hip/hip_runtime.h>
#include <hip/hip_bf16.h>

// out[b,s,n] = x[b,s,n] * w[n];  x: (4,4096,4096) fp32, w: (4096,) fp32.
// Pure HBM-bound elementwise: 256 MiB read + 256 MiB write, w (16 KiB) L1-resident.
// R3: same as R2 but with native ext_vector_type for the nontemporal builtins
// (HIP_vector_type is a class -> rejected by __builtin_nontemporal_*).
// n4/2 = 8388608 divisible by 1024 -> both halves share one w4 index.

typedef float f4 __attribute__((ext_vector_type(4)));

__global__ __launch_bounds__(256) void mulw_kernel(
    const f4* __restrict__ x4,
    const f4* __restrict__ w4,   // 1024 f4 = 4096 floats
    f4* __restrict__ out4,
    unsigned int half)           // n4/2 in f4 units
{
    unsigned int i = blockIdx.x * 256u + threadIdx.x;
    if (i >= half) return;

    f4 w = w4[i & 1023u];        // shared by both halves (half % 1024 == 0)

    f4 a = __builtin_nontemporal_load(&x4[i]);
    f4 b = __builtin_nontemporal_load(&x4[i + half]);

    a *= w;
    b *= w;

    __builtin_nontemporal_store(a, &out4[i]);
    __builtin_nontemporal_store(b, &out4[i + half]);
}

extern "C" void kernel_launch(void* const* d_in, const int* in_sizes, int n_in,
                              void* d_out, int out_size, void* d_ws, size_t ws_size,
                              hipStream_t stream) {
    const f4* x4 = (const f4*)d_in[0];
    const f4* w4 = (const f4*)d_in[1];
    f4* out4 = (f4*)d_out;

    // total elements = 4*4096*4096 = 67,108,864 ; /4 per f4 ; /2 per thread
    unsigned int n4 = (unsigned int)(out_size / 4);
    unsigned int half = n4 / 2;                       // 8,388,608
    unsigned int threads = 256;
    unsigned int blocks = (half + threads - 1) / threads;  // 32,768

    mulw_kernel<<<blocks, threads, 0, stream>>>(x4, w4, out4, half);
}